// Round 8
// baseline (585.531 us; speedup 1.0000x reference)
//
#include <hip/hip_runtime.h>
#include <stdint.h>

#define S_LEN 256
#define DIM   128
#define EPSL  1e-5f

typedef __bf16 bf16x8 __attribute__((ext_vector_type(8)));
typedef float  f32x4  __attribute__((ext_vector_type(4)));

__device__ __forceinline__ unsigned short f2bf_bits(float f) {
  union { float f; unsigned int u; } v; v.f = f;
  unsigned int r = v.u + 0x7fffu + ((v.u >> 16) & 1u);   // RTNE (init paths)
  return (unsigned short)(r >> 16);
}
__device__ __forceinline__ unsigned f2bf_rhu(float f) {
  return (__float_as_uint(f) + 0x8000u) >> 16;
}
__device__ __forceinline__ unsigned pack_rhu(float lo, float hi) {
  return __builtin_amdgcn_perm(__float_as_uint(hi) + 0x8000u,
                               __float_as_uint(lo) + 0x8000u, 0x07060302u);
}
// tanh(x) = 1 - 2/(e^{2x}+1): ~1e-6 rel err, exact at +-inf.
__device__ __forceinline__ float tanh_fast(float x) {
  float e = __expf(2.f * x);
  return 1.f - 2.f * __builtin_amdgcn_rcpf(e + 1.f);
}

template<int CTRL>
__device__ __forceinline__ float dpp_rot_add(float v) {
  int r = __builtin_amdgcn_update_dpp(0, __float_as_int(v), CTRL, 0xF, 0xF, true);
  return v + __int_as_float(r);
}
template<int CTRL>
__device__ __forceinline__ float dpp_rot_max(float v) {
  int r = __builtin_amdgcn_update_dpp(0, __float_as_int(v), CTRL, 0xF, 0xF, true);
  return fmaxf(v, __int_as_float(r));
}
__device__ __forceinline__ float dpp_sum16(float v) {
  v = dpp_rot_add<0x124>(v); v = dpp_rot_add<0x128>(v);
  v = dpp_rot_add<0x39>(v);  v = dpp_rot_add<0x4E>(v);
  return v;
}
__device__ __forceinline__ float dpp_max16(float v) {
  v = dpp_rot_max<0x124>(v); v = dpp_rot_max<0x128>(v);
  v = dpp_rot_max<0x39>(v);  v = dpp_rot_max<0x4E>(v);
  return v;
}
template<int CTRL>
__device__ __forceinline__ void red_level7(float& s, float& sq, float* d) {
  s  = dpp_rot_add<CTRL>(s);
  sq = dpp_rot_add<CTRL>(sq);
#pragma unroll
  for (int j = 0; j < 5; j++) d[j] = dpp_rot_add<CTRL>(d[j]);
}
template<int JJ>
__device__ __forceinline__ float bcast16(float v) {
  int r = __builtin_amdgcn_ds_swizzle(__float_as_int(v), (JJ << 5) | 0x10);
  return __int_as_float(r);
}

union Frag8 { unsigned short us[8]; bf16x8 v; int4 i4; };

// ============ rnn_main: R5 structure, e gathered to REGISTERS ===============
// Core blocks (0-63), 8 waves (2/SIMD — measured optimum). vs the verified
// 177 us R5 kernel, ONE change: the e path no longer goes through LDS. Each
// wave gathers its own e A-frags straight from emb (L3-resident) into
// registers (8 x float4 per step, issued 2 steps ahead of use; xid
// prefetched one further step so the x_tile ds_read is off-path), packs with
// pack_rhu in-register (bit-identical values to the staged path), and runs
// the same depth-4 xpacc MFMA chain. This removes 4 of the 8 ds_read_b128
// per wave per step (the largest term in the per-CU step envelope: 64 ->
// 32 b128 reads/step) plus all staging writes, trading them for gathered
// L2/L3 loads on the otherwise-idle vector-memory pipe. The serial h chain,
// swizzles, hout stores, chunk-flag protocol, and tail are byte-identical
// to R5.
__global__ __launch_bounds__(512, 2)
void rnn_main(const int* __restrict__ x, const float* __restrict__ emb,
              const float* __restrict__ Wih1, const float* __restrict__ bih1,
              const float* __restrict__ Whh1, const float* __restrict__ bhh1,
              const float* __restrict__ g1, const float* __restrict__ be1,
              const float* __restrict__ Wih2, const float* __restrict__ bih2,
              const float* __restrict__ Whh2, const float* __restrict__ bhh2,
              const float* __restrict__ g2, const float* __restrict__ be2,
              unsigned short* __restrict__ hout, int* flags,
              float* __restrict__ out)
{
  __shared__ __align__(16) unsigned short h_bf[2][16 * 128];   // 8 KB
  __shared__ int x_tile[16 * 256];                             // 16 KB
  __shared__ __align__(16) float p_lds[8][2][32][8];           // 16 KB (tail)

  const int tid  = threadIdx.x;
  const int wave = tid >> 6;
  const int lane = tid & 63;
  const int l15  = lane & 15;
  const int q    = lane >> 4;

  if (blockIdx.x < 64) {
    // ========================= CORE ROLE =========================
    const int r0 = blockIdx.x * 16;
    for (int i = tid; i < 16 * 256; i += 512)
      x_tile[i] = x[(size_t)(r0 + (i >> 8)) * S_LEN + (i & 255)];
    for (int i = tid; i < 16 * 128; i += 512) h_bf[1][i] = 0;  // h_{-1} = 0

    const int n1 = wave * 16 + l15;
    const float bias1v = bih1[n1] + bhh1[n1];
    bf16x8 wh[4], wih[4];
#pragma unroll
    for (int kt = 0; kt < 4; kt++) {
      int k0 = kt * 32 + q * 8;
      Frag8 fh, fa;
#pragma unroll
      for (int j = 0; j < 8; j++) {
        fh.us[j] = f2bf_bits(Whh1[n1 * DIM + k0 + j]);
        fa.us[j] = f2bf_bits(Wih1[n1 * DIM + k0 + j]);
      }
      wh[kt] = fh.v; wih[kt] = fa.v;
    }
    __syncthreads();                     // x_tile, h_bf[1] ready

    // ---- per-wave register e pipeline (no LDS e staging) ----
    float4 eldA[8], eldB[8];             // f32 e rows, 2-step-ahead dbuf
    Frag8  frag[4];                      // packed bf16 A-frags for e_{t+1}
    auto eload = [&](float4* e, int xid) {
      const float* pe = emb + (size_t)xid * DIM + q * 8;
#pragma unroll
      for (int kt = 0; kt < 4; kt++) {   // elem j = e[l15][kt*32 + q*8 + j]
        e[kt * 2]     = *(const float4*)(pe + kt * 32);
        e[kt * 2 + 1] = *(const float4*)(pe + kt * 32 + 4);
      }
    };
    auto epack = [&](const float4* e) {  // same pack_rhu bits as staged path
#pragma unroll
      for (int kt = 0; kt < 4; kt++) {
        frag[kt].i4.x = (int)pack_rhu(e[kt * 2].x,     e[kt * 2].y);
        frag[kt].i4.y = (int)pack_rhu(e[kt * 2].z,     e[kt * 2].w);
        frag[kt].i4.z = (int)pack_rhu(e[kt * 2 + 1].x, e[kt * 2 + 1].y);
        frag[kt].i4.w = (int)pack_rhu(e[kt * 2 + 1].z, e[kt * 2 + 1].w);
      }
    };
    f32x4 xpacc;
    auto produce = [&]() {               // xp = bias + e@Wih^T (R5 order)
      f32x4 a = {bias1v, bias1v, bias1v, bias1v};
#pragma unroll
      for (int kt = 0; kt < 4; kt++)
        a = __builtin_amdgcn_mfma_f32_16x16x32_bf16(frag[kt].v, wih[kt], a, 0, 0, 0);
      xpacc = a;
    };
    auto sstep = [&](int t) {            // serial chain — identical to R5
      f32x4 acc = xpacc;
      const int rb = (t + 1) & 1;        // h_{t-1}
#pragma unroll
      for (int kt = 0; kt < 4; kt++) {
        int sw = (((kt * 4 + q) ^ l15) & 15) * 8;
        bf16x8 ahf = *(const bf16x8*)&h_bf[rb][l15 * 128 + sw];
        acc = __builtin_amdgcn_mfma_f32_16x16x32_bf16(ahf, wh[kt], acc, 0, 0, 0);
      }
      const int wb = t & 1;
      const int oct = n1 >> 3;
#pragma unroll
      for (int r = 0; r < 4; r++) {      // D-layout: row = q*4 + r, col = l15
        int row = q * 4 + r;
        unsigned short us = (unsigned short)f2bf_rhu(tanh_fast(acc[r]));
        h_bf[wb][row * 128 + ((oct ^ row) & 15) * 8 + (n1 & 7)] = us;
        hout[((size_t)(r0 + row) * S_LEN + t) * DIM + n1] = us;  // off-chain
      }
    };

    // ---- prologue: xpacc=xp(0), frag=e(1), eldA=e(2), eldB=e(3) ----
    eload(eldA, x_tile[l15 * 256 + 0]); epack(eldA); produce();
    eload(eldA, x_tile[l15 * 256 + 1]); epack(eldA);
    eload(eldA, x_tile[l15 * 256 + 2]);
    eload(eldB, x_tile[l15 * 256 + 3]);
    int xidA = x_tile[l15 * 256 + 4];    // xid for eldA's next load (t0+4)
    int xidB = x_tile[l15 * 256 + 5];    // xid for eldB's next load (t1+4)
    asm volatile("s_waitcnt lgkmcnt(0)\n\ts_barrier" ::: "memory");

    for (int tp = 0; tp < S_LEN / 2; tp++) {
      const int t0 = 2 * tp, t1 = t0 + 1;
      // -------- even step --------
      sstep(t0);
      produce();                          // xp(t0+1) from frag=e(t0+1)
      if (t0 + 2 < S_LEN) epack(eldA);    // frag <- e(t0+2)
      if (t0 + 4 < S_LEN) eload(eldA, xidA);             // eldA <- e(t0+4)
      if (t0 + 6 < S_LEN) xidA = x_tile[l15 * 256 + t0 + 6];
      asm volatile("s_waitcnt lgkmcnt(0)\n\ts_barrier" ::: "memory");
      // -------- odd step --------
      sstep(t1);
      if (t1 + 1 < S_LEN) produce();      // xp(t1+1) from frag=e(t1+1)
      if (t1 + 2 < S_LEN) epack(eldB);    // frag <- e(t1+2)
      if (t1 + 4 < S_LEN) eload(eldB, xidB);             // eldB <- e(t1+4)
      if (t1 + 6 < S_LEN) xidB = x_tile[l15 * 256 + t1 + 6];
      // chunk boundary (t1 = 32c+31): drain h stores, then publish flag.
      if (flags != nullptr && (t1 & 31) == 31)
        asm volatile("s_waitcnt vmcnt(0)" ::: "memory");
      asm volatile("s_waitcnt lgkmcnt(0)\n\ts_barrier" ::: "memory");
      if (flags != nullptr && (t1 & 31) == 31 && tid == 0)
        __hip_atomic_store(&flags[blockIdx.x * 8 + (t1 >> 5)], (t1 >> 5) + 1,
                           __ATOMIC_RELEASE, __HIP_MEMORY_SCOPE_AGENT);
    }
  } else {
    // ========================= TAIL ROLE (R5-verified) =========================
    const int bt = blockIdx.x - 64;      // paired core block
    float w2g[5][8], Gs[5], Bs[5], wrow[5];
#pragma unroll
    for (int j = 0; j < 8; j++) {
      int c = l15 * 8 + j;               // plain row-major channels
      float gc = g1[c];
#pragma unroll
      for (int jj = 0; jj < 5; jj++) w2g[jj][j] = Wih2[jj * DIM + c] * gc;
    }
#pragma unroll
    for (int jj = 0; jj < 5; jj++) { Gs[jj] = 0.f; Bs[jj] = 0.f; }
    for (int c = 0; c < DIM; c++) {
      float gc = g1[c], bc = be1[c];
#pragma unroll
      for (int jj = 0; jj < 5; jj++) {
        float w = Wih2[jj * DIM + c];
        Gs[jj] += w * gc; Bs[jj] += w * bc;
      }
    }
    const float validf = (l15 < 5) ? 1.f : 0.f;
    float t2_l = 0.f, g2_l = 0.f, be2_l = 0.f;
    if (l15 < 5) {
      t2_l = bih2[l15] + bhh2[l15];
      g2_l = g2[l15]; be2_l = be2[l15];
#pragma unroll
      for (int jj = 0; jj < 5; jj++) wrow[jj] = Whh2[l15 * 5 + jj];
    } else {
#pragma unroll
      for (int jj = 0; jj < 5; jj++) wrow[jj] = 0.f;
    }
    float h2rep[5] = {0, 0, 0, 0, 0}, pool_l = 0.f;
    const int row_l = 2 * wave + (q & 1);          // this group's row
    const unsigned short* hb =
        hout + (size_t)(bt * 16 + row_l) * S_LEN * DIM;
    const int idx = (l15 < 5) ? l15 : 0;

    for (int c8 = 0; c8 < 8; c8++) {
      if (tid == 0) {                    // poisoned flag is negative: waits
        while (__hip_atomic_load(&flags[bt * 8 + c8], __ATOMIC_RELAXED,
                                 __HIP_MEMORY_SCOPE_AGENT) < c8 + 1)
          __builtin_amdgcn_s_sleep(2);
      }
      __syncthreads();
      __builtin_amdgcn_fence(__ATOMIC_ACQUIRE, "agent");   // reader-side inv
      // phase A: LN1+proj for this chunk (2 rows x 32 t over 4 groups)
      for (int tt = 0; tt < 16; tt++) {
        int toff = tt * 2 + (q >> 1);
        uint4 cur = *(const uint4*)(hb + (size_t)(c8 * 32 + toff) * DIM + l15 * 8);
        float hv[8];
        hv[0] = __uint_as_float(cur.x << 16); hv[1] = __uint_as_float(cur.x & 0xffff0000u);
        hv[2] = __uint_as_float(cur.y << 16); hv[3] = __uint_as_float(cur.y & 0xffff0000u);
        hv[4] = __uint_as_float(cur.z << 16); hv[5] = __uint_as_float(cur.z & 0xffff0000u);
        hv[6] = __uint_as_float(cur.w << 16); hv[7] = __uint_as_float(cur.w & 0xffff0000u);
        float s = 0.f, sq = 0.f, d[5] = {0, 0, 0, 0, 0};
#pragma unroll
        for (int j = 0; j < 8; j++) {
          float v = hv[j];
          s += v; sq += v * v;
#pragma unroll
          for (int jj = 0; jj < 5; jj++) d[jj] = fmaf(w2g[jj][j], v, d[jj]);
        }
        red_level7<0x124>(s, sq, d);
        red_level7<0x128>(s, sq, d);
        red_level7<0x39>(s, sq, d);
        red_level7<0x4E>(s, sq, d);
        float mean = s * (1.f / 128.f);
        float var  = sq * (1.f / 128.f) - mean * mean;
        float rstd = rsqrtf(var + EPSL);
        float p[5];
#pragma unroll
        for (int jj = 0; jj < 5; jj++)
          p[jj] = rstd * (d[jj] - mean * Gs[jj]) + Bs[jj];
        float psel = (l15 == 0) ? p[0] : (l15 == 1) ? p[1] :
                     (l15 == 2) ? p[2] : (l15 == 3) ? p[3] : p[4];
        if (l15 < 5) p_lds[wave][q & 1][toff][l15] = psel;
      }
      asm volatile("s_waitcnt lgkmcnt(0)" ::: "memory");   // wave-local
      // phase B: 32 serial RNN2/LN2/pool steps (group-local, 1 tanh/step)
      for (int s = 0; s < 32; s++) {
        float pv = p_lds[wave][q & 1][s][idx];
        float a = pv + t2_l;
#pragma unroll
        for (int jj = 0; jj < 5; jj++) a = fmaf(wrow[jj], h2rep[jj], a);
        float xn = tanh_fast(a);
        float s2 = dpp_sum16(xn * validf) * 0.2f;
        float dd = xn - s2;
        float v2 = dpp_sum16(dd * dd * validf) * 0.2f;
        float r2 = rsqrtf(v2 + EPSL);
        pool_l += dd * r2 * g2_l + be2_l;
        h2rep[0] = bcast16<0>(xn); h2rep[1] = bcast16<1>(xn);
        h2rep[2] = bcast16<2>(xn); h2rep[3] = bcast16<3>(xn);
        h2rep[4] = bcast16<4>(xn);
      }
    }
    float lg = pool_l * (1.f / 256.f);
    float mx = dpp_max16((l15 < 5) ? lg : -3.0e38f);
    float e  = (l15 < 5) ? __expf(lg - mx) : 0.f;
    float sm = dpp_sum16(e);
    if (q < 2 && l15 < 5)
      out[(size_t)(bt * 16 + row_l) * 5 + l15] = e / sm;
  }
}

// ============ rnn_tail_r11: fallback tail (ws too small for flags) =========
__global__ __launch_bounds__(256, 2)
void rnn_tail_r11(const unsigned short* __restrict__ hall,
                  const float* __restrict__ g1,  const float* __restrict__ be1,
                  const float* __restrict__ Wih2, const float* __restrict__ bih2,
                  const float* __restrict__ Whh2, const float* __restrict__ bhh2,
                  const float* __restrict__ g2,  const float* __restrict__ be2,
                  float* __restrict__ out)
{
  __shared__ float p_lds[4][4][8];
  const int tid  = threadIdx.x;
  const int wave = tid >> 6;
  const int lane = tid & 63;
  const int l15  = lane & 15;
  const int q    = lane >> 4;
  const int b    = blockIdx.x * 4 + wave;

  float w2g[5][8], Gs[5], Bs[5], wrow[5];
#pragma unroll
  for (int j = 0; j < 8; j++) {
    int c = l15 * 8 + j;
    float gc = g1[c];
#pragma unroll
    for (int jj = 0; jj < 5; jj++) w2g[jj][j] = Wih2[jj * DIM + c] * gc;
  }
#pragma unroll
  for (int jj = 0; jj < 5; jj++) { Gs[jj] = 0.f; Bs[jj] = 0.f; }
  for (int c = 0; c < DIM; c++) {
    float gc = g1[c], bc = be1[c];
#pragma unroll
    for (int jj = 0; jj < 5; jj++) {
      float w = Wih2[jj * DIM + c];
      Gs[jj] += w * gc; Bs[jj] += w * bc;
    }
  }
  const float validf = (l15 < 5) ? 1.f : 0.f;
  float t2_l = 0.f, g2_l = 0.f, be2_l = 0.f;
  if (l15 < 5) {
    t2_l = bih2[l15] + bhh2[l15];
    g2_l = g2[l15]; be2_l = be2[l15];
#pragma unroll
    for (int jj = 0; jj < 5; jj++) wrow[jj] = Whh2[l15 * 5 + jj];
  } else {
#pragma unroll
    for (int jj = 0; jj < 5; jj++) wrow[jj] = 0.f;
  }
  float h2rep[5];
#pragma unroll
  for (int jj = 0; jj < 5; jj++) h2rep[jj] = 0.f;
  float pool_l = 0.f;

  const unsigned short* hb = hall + (size_t)b * S_LEN * DIM;
  uint4 hpre = *(const uint4*)(hb + (size_t)q * DIM + l15 * 8);

  for (int t0 = 0; t0 < S_LEN; t0 += 4) {
    uint4 cur = hpre;
    if (t0 + 4 < S_LEN)
      hpre = *(const uint4*)(hb + (size_t)(t0 + 4 + q) * DIM + l15 * 8);
    float hv[8];
    hv[0] = __uint_as_float(cur.x << 16); hv[1] = __uint_as_float(cur.x & 0xffff0000u);
    hv[2] = __uint_as_float(cur.y << 16); hv[3] = __uint_as_float(cur.y & 0xffff0000u);
    hv[4] = __uint_as_float(cur.z << 16); hv[5] = __uint_as_float(cur.z & 0xffff0000u);
    hv[6] = __uint_as_float(cur.w << 16); hv[7] = __uint_as_float(cur.w & 0xffff0000u);
    float s = 0.f, sq = 0.f, d[5] = {0, 0, 0, 0, 0};
#pragma unroll
    for (int j = 0; j < 8; j++) {
      float v = hv[j];
      s += v; sq += v * v;
#pragma unroll
      for (int jj = 0; jj < 5; jj++) d[jj] = fmaf(w2g[jj][j], v, d[jj]);
    }
    red_level7<0x124>(s, sq, d);
    red_level7<0x128>(s, sq, d);
    red_level7<0x39>(s, sq, d);
    red_level7<0x4E>(s, sq, d);
    float mean = s * (1.f / 128.f);
    float var  = sq * (1.f / 128.f) - mean * mean;
    float rstd = rsqrtf(var + EPSL);
    float p[5];
#pragma unroll
    for (int jj = 0; jj < 5; jj++)
      p[jj] = rstd * (d[jj] - mean * Gs[jj]) + Bs[jj];
    float psel = (l15 == 0) ? p[0] : (l15 == 1) ? p[1] :
                 (l15 == 2) ? p[2] : (l15 == 3) ? p[3] : p[4];
    if (l15 < 5) p_lds[wave][q][l15] = psel;
    asm volatile("s_waitcnt lgkmcnt(0)" ::: "memory");
    const int idx = (l15 < 5) ? l15 : 0;
#pragma unroll
    for (int g = 0; g < 4; g++) {
      float pv = p_lds[wave][g][idx];
      float a = pv + t2_l;
#pragma unroll
      for (int jj = 0; jj < 5; jj++) a = fmaf(wrow[jj], h2rep[jj], a);
      float xn = tanh_fast(a);
      float s2 = dpp_sum16(xn * validf) * 0.2f;
      float dd = xn - s2;
      float v2 = dpp_sum16(dd * dd * validf) * 0.2f;
      float r2 = rsqrtf(v2 + EPSL);
      pool_l += dd * r2 * g2_l + be2_l;
      h2rep[0] = bcast16<0>(xn); h2rep[1] = bcast16<1>(xn);
      h2rep[2] = bcast16<2>(xn); h2rep[3] = bcast16<3>(xn);
      h2rep[4] = bcast16<4>(xn);
    }
  }

  float lg = pool_l * (1.f / 256.f);
  float mx = dpp_max16((l15 < 5) ? lg : -3.0e38f);
  float e  = (l15 < 5) ? __expf(lg - mx) : 0.f;
  float sm = dpp_sum16(e);
  if (q == 0 && l15 < 5) out[(size_t)b * 5 + l15] = e / sm;
}

extern "C" void kernel_launch(void* const* d_in, const int* in_sizes, int n_in,
                              void* d_out, int out_size, void* d_ws, size_t ws_size,
                              hipStream_t stream) {
  (void)in_sizes; (void)n_in; (void)out_size;
  const int*   x    = (const int*)  d_in[0];
  const float* emb  = (const float*)d_in[1];
  const float* Wih1 = (const float*)d_in[2];
  const float* bih1 = (const float*)d_in[3];
  const float* Whh1 = (const float*)d_in[4];
  const float* bhh1 = (const float*)d_in[5];
  const float* g1   = (const float*)d_in[6];
  const float* be1  = (const float*)d_in[7];
  const float* Wih2 = (const float*)d_in[8];
  const float* bih2 = (const float*)d_in[9];
  const float* Whh2 = (const float*)d_in[10];
  const float* bhh2 = (const float*)d_in[11];
  const float* g2   = (const float*)d_in[12];
  const float* be2  = (const float*)d_in[13];
  float* out = (float*)d_out;

  const size_t HBYTES = (size_t)1024 * S_LEN * DIM * 2;   // 64 MiB bf16 h
  unsigned short* hws = (unsigned short*)d_ws;

  if (ws_size >= HBYTES + 4096) {
    int* flags = (int*)((char*)d_ws + HBYTES);
    rnn_main<<<dim3(128), dim3(512), 0, stream>>>(
        x, emb, Wih1, bih1, Whh1, bhh1, g1, be1,
        Wih2, bih2, Whh2, bhh2, g2, be2, hws, flags, out);
  } else {
    // fallback: core-only mode (flags = nullptr) + R11 two-kernel tail
    rnn_main<<<dim3(64), dim3(512), 0, stream>>>(
        x, emb, Wih1, bih1, Whh1, bhh1, g1, be1,
        Wih2, bih2, Whh2, bhh2, g2, be2, hws, nullptr, out);
    rnn_tail_r11<<<dim3(256), dim3(256), 0, stream>>>(
        hws, g1, be1, Wih2, bih2, Whh2, bhh2, g2, be2, out);
  }
}

// Round 9
// 255.519 us; speedup vs baseline: 2.2915x; 2.2915x over previous
//
#include <hip/hip_runtime.h>
#include <stdint.h>

#define S_LEN 256
#define DIM   128
#define EPSL  1e-5f

typedef __bf16 bf16x8 __attribute__((ext_vector_type(8)));
typedef float  f32x4  __attribute__((ext_vector_type(4)));

__device__ __forceinline__ unsigned short f2bf_bits(float f) {
  union { float f; unsigned int u; } v; v.f = f;
  unsigned int r = v.u + 0x7fffu + ((v.u >> 16) & 1u);   // RTNE (init paths)
  return (unsigned short)(r >> 16);
}
__device__ __forceinline__ unsigned f2bf_rhu(float f) {
  return (__float_as_uint(f) + 0x8000u) >> 16;
}
__device__ __forceinline__ unsigned pack_rhu(float lo, float hi) {
  return __builtin_amdgcn_perm(__float_as_uint(hi) + 0x8000u,
                               __float_as_uint(lo) + 0x8000u, 0x07060302u);
}
// tanh(x) = 1 - 2/(e^{2x}+1): ~1e-6 rel err, exact at +-inf.
__device__ __forceinline__ float tanh_fast(float x) {
  float e = __expf(2.f * x);
  return 1.f - 2.f * __builtin_amdgcn_rcpf(e + 1.f);
}

template<int CTRL>
__device__ __forceinline__ float dpp_rot_add(float v) {
  int r = __builtin_amdgcn_update_dpp(0, __float_as_int(v), CTRL, 0xF, 0xF, true);
  return v + __int_as_float(r);
}
template<int CTRL>
__device__ __forceinline__ float dpp_rot_max(float v) {
  int r = __builtin_amdgcn_update_dpp(0, __float_as_int(v), CTRL, 0xF, 0xF, true);
  return fmaxf(v, __int_as_float(r));
}
__device__ __forceinline__ float dpp_sum16(float v) {
  v = dpp_rot_add<0x124>(v); v = dpp_rot_add<0x128>(v);
  v = dpp_rot_add<0x39>(v);  v = dpp_rot_add<0x4E>(v);
  return v;
}
__device__ __forceinline__ float dpp_max16(float v) {
  v = dpp_rot_max<0x124>(v); v = dpp_rot_max<0x128>(v);
  v = dpp_rot_max<0x39>(v);  v = dpp_rot_max<0x4E>(v);
  return v;
}
template<int CTRL>
__device__ __forceinline__ void red_level7(float& s, float& sq, float* d) {
  s  = dpp_rot_add<CTRL>(s);
  sq = dpp_rot_add<CTRL>(sq);
#pragma unroll
  for (int j = 0; j < 5; j++) d[j] = dpp_rot_add<CTRL>(d[j]);
}
template<int JJ>
__device__ __forceinline__ float bcast16(float v) {
  int r = __builtin_amdgcn_ds_swizzle(__float_as_int(v), (JJ << 5) | 0x10);
  return __int_as_float(r);
}

union Frag8 { unsigned short us[8]; bf16x8 v; int4 i4; };

// ================= rnn_main: R0 structure + BALANCED staging ================
// Core blocks (0-63), 8 waves (2/SIMD — measured optimum across the R0-R8
// structural sweep: 16w split 245-260us, 4w 215us, 2w 317us, barrierless
// 1-wave 455us, xp-via-HBM 280us, reg-gathered e 504us; this structure
// 177us). The e-staging pipeline is spread across ALL 8 waves: each wave
// stages 2 batch rows x half-octet granularity (one float4 gather, 2 packs,
// one ds_write_b64 per step). Serial chain: xpacc seed + depth-4 MFMA +
// tanh + swizzled h_bf write + off-chain hout store, one barrier per step.
// Chunk flags publish every 32 steps for the concurrent tail blocks (64-127).
__global__ __launch_bounds__(512, 2)
void rnn_main(const int* __restrict__ x, const float* __restrict__ emb,
              const float* __restrict__ Wih1, const float* __restrict__ bih1,
              const float* __restrict__ Whh1, const float* __restrict__ bhh1,
              const float* __restrict__ g1, const float* __restrict__ be1,
              const float* __restrict__ Wih2, const float* __restrict__ bih2,
              const float* __restrict__ Whh2, const float* __restrict__ bhh2,
              const float* __restrict__ g2, const float* __restrict__ be2,
              unsigned short* __restrict__ hout, int* flags,
              float* __restrict__ out)
{
  __shared__ __align__(16) unsigned short h_bf[2][16 * 128];   // 8 KB
  __shared__ __align__(16) unsigned short e_bf[2][16 * 128];   // 8 KB
  __shared__ int x_tile[16 * 256];                             // 16 KB
  __shared__ __align__(16) float p_lds[8][2][32][8];           // 16 KB (tail)

  const int tid  = threadIdx.x;
  const int wave = tid >> 6;
  const int lane = tid & 63;
  const int l15  = lane & 15;
  const int q    = lane >> 4;

  if (blockIdx.x < 64) {
    // ========================= CORE ROLE =========================
    const int r0 = blockIdx.x * 16;
    for (int i = tid; i < 16 * 256; i += 512)
      x_tile[i] = x[(size_t)(r0 + (i >> 8)) * S_LEN + (i & 255)];
    for (int i = tid; i < 16 * 128; i += 512) h_bf[1][i] = 0;  // h_{-1} = 0

    const int n1 = wave * 16 + l15;
    const float bias1v = bih1[n1] + bhh1[n1];
    bf16x8 wh[4], wih[4];
#pragma unroll
    for (int kt = 0; kt < 4; kt++) {
      int k0 = kt * 32 + q * 8;
      Frag8 fh, fa;
#pragma unroll
      for (int j = 0; j < 8; j++) {
        fh.us[j] = f2bf_bits(Whh1[n1 * DIM + k0 + j]);
        fa.us[j] = f2bf_bits(Wih1[n1 * DIM + k0 + j]);
      }
      wh[kt] = fh.v; wih[kt] = fa.v;
    }

    // ---- balanced staging geometry: every wave stages 2 rows, float4/lane
    const int srow = wave * 2 + (lane >> 5);     // batch row (0..15)
    const int soct = (lane >> 1) & 15;           // octet within the row
    const int ssub = lane & 1;                   // which half of the octet
    const int sdst = srow * 128 + ((soct ^ srow) & 15) * 8 + ssub * 4;
    float4 pf[2];
    __syncthreads();

    {                                  // stage e[0],e[1]; preload e[2],e[3]
      float4 ta, tb;
      { int xid = x_tile[srow * 256 + 0];
        ta = *(const float4*)(emb + (size_t)xid * DIM + soct * 8 + ssub * 4); }
      { int xid = x_tile[srow * 256 + 1];
        tb = *(const float4*)(emb + (size_t)xid * DIM + soct * 8 + ssub * 4); }
      { int xid = x_tile[srow * 256 + 2];
        pf[0] = *(const float4*)(emb + (size_t)xid * DIM + soct * 8 + ssub * 4); }
      { int xid = x_tile[srow * 256 + 3];
        pf[1] = *(const float4*)(emb + (size_t)xid * DIM + soct * 8 + ssub * 4); }
      int2 pa, pb;
      pa.x = (int)pack_rhu(ta.x, ta.y); pa.y = (int)pack_rhu(ta.z, ta.w);
      pb.x = (int)pack_rhu(tb.x, tb.y); pb.y = (int)pack_rhu(tb.z, tb.w);
      *(int2*)&e_bf[0][sdst] = pa;
      *(int2*)&e_bf[1][sdst] = pb;
    }
    __syncthreads();

    f32x4 xpacc = {bias1v, bias1v, bias1v, bias1v};
#pragma unroll
    for (int kt = 0; kt < 4; kt++) {
      int sw = (((kt * 4 + q) ^ l15) & 15) * 8;
      bf16x8 ae = *(const bf16x8*)&e_bf[0][l15 * 128 + sw];
      xpacc = __builtin_amdgcn_mfma_f32_16x16x32_bf16(ae, wih[kt], xpacc, 0, 0, 0);
    }
    asm volatile("s_waitcnt lgkmcnt(0)\n\ts_barrier" ::: "memory");

#pragma unroll 2
    for (int t = 0; t < S_LEN; t++) {
      // ---- serial core: acc seeded with xpacc, ONE depth-4 chain ----
      f32x4 acc = xpacc;
      {
        const int rb = (t + 1) & 1;      // h_{t-1}
#pragma unroll
        for (int kt = 0; kt < 4; kt++) {
          int sw = (((kt * 4 + q) ^ l15) & 15) * 8;
          bf16x8 ahf = *(const bf16x8*)&h_bf[rb][l15 * 128 + sw];
          acc = __builtin_amdgcn_mfma_f32_16x16x32_bf16(ahf, wh[kt], acc, 0, 0, 0);
        }
        const int wb = t & 1;
        const int oct = n1 >> 3;
#pragma unroll
        for (int r = 0; r < 4; r++) {    // D-layout: row = q*4 + r, col = l15
          int row = q * 4 + r;
          unsigned short us = (unsigned short)f2bf_rhu(tanh_fast(acc[r]));
          h_bf[wb][row * 128 + ((oct ^ row) & 15) * 8 + (n1 & 7)] = us;
          hout[((size_t)(r0 + row) * S_LEN + t) * DIM + n1] = us;  // off-chain
        }
      }

      if (t + 1 < S_LEN) {               // e_{t+1}@Wih into regs (off-chain)
        f32x4 a = {bias1v, bias1v, bias1v, bias1v};
#pragma unroll
        for (int kt = 0; kt < 4; kt++) {
          int sw = (((kt * 4 + q) ^ l15) & 15) * 8;
          bf16x8 ae = *(const bf16x8*)&e_bf[(t + 1) & 1][l15 * 128 + sw];
          a = __builtin_amdgcn_mfma_f32_16x16x32_bf16(ae, wih[kt], a, 0, 0, 0);
        }
        xpacc = a;
      }

      {                                  // balanced staging (all 8 waves)
        if (t + 2 < S_LEN) {             // stage e[t+2] (gathered at t-2)
          int2 pk;
          pk.x = (int)pack_rhu(pf[t & 1].x, pf[t & 1].y);
          pk.y = (int)pack_rhu(pf[t & 1].z, pf[t & 1].w);
          *(int2*)&e_bf[t & 1][sdst] = pk;
        }
        if (t + 4 < S_LEN) {             // issue gather e[t+4] (2-step cover)
          int xid = x_tile[srow * 256 + t + 4];
          pf[t & 1] = *(const float4*)(emb + (size_t)xid * DIM + soct * 8 + ssub * 4);
        }
      }
      // chunk boundary: drain this wave's h stores before the barrier so the
      // post-barrier flag publish covers the whole block's chunk.
      if (flags != nullptr && (t & 31) == 31)
        asm volatile("s_waitcnt vmcnt(0)" ::: "memory");
      asm volatile("s_waitcnt lgkmcnt(0)\n\ts_barrier" ::: "memory");
      if (flags != nullptr && (t & 31) == 31 && tid == 0)
        __hip_atomic_store(&flags[blockIdx.x * 8 + (t >> 5)], (t >> 5) + 1,
                           __ATOMIC_RELEASE, __HIP_MEMORY_SCOPE_AGENT);
    }
  } else {
    // ========================= TAIL ROLE =========================
    const int bt = blockIdx.x - 64;      // paired core block
    float w2g[5][8], Gs[5], Bs[5], wrow[5];
#pragma unroll
    for (int j = 0; j < 8; j++) {
      int c = l15 * 8 + j;               // plain row-major channels
      float gc = g1[c];
#pragma unroll
      for (int jj = 0; jj < 5; jj++) w2g[jj][j] = Wih2[jj * DIM + c] * gc;
    }
#pragma unroll
    for (int jj = 0; jj < 5; jj++) { Gs[jj] = 0.f; Bs[jj] = 0.f; }
    for (int c = 0; c < DIM; c++) {
      float gc = g1[c], bc = be1[c];
#pragma unroll
      for (int jj = 0; jj < 5; jj++) {
        float w = Wih2[jj * DIM + c];
        Gs[jj] += w * gc; Bs[jj] += w * bc;
      }
    }
    const float validf = (l15 < 5) ? 1.f : 0.f;
    float t2_l = 0.f, g2_l = 0.f, be2_l = 0.f;
    if (l15 < 5) {
      t2_l = bih2[l15] + bhh2[l15];
      g2_l = g2[l15]; be2_l = be2[l15];
#pragma unroll
      for (int jj = 0; jj < 5; jj++) wrow[jj] = Whh2[l15 * 5 + jj];
    } else {
#pragma unroll
      for (int jj = 0; jj < 5; jj++) wrow[jj] = 0.f;
    }
    float h2rep[5] = {0, 0, 0, 0, 0}, pool_l = 0.f;
    const int row_l = 2 * wave + (q & 1);          // this group's row
    const unsigned short* hb =
        hout + (size_t)(bt * 16 + row_l) * S_LEN * DIM;
    const int idx = (l15 < 5) ? l15 : 0;

    for (int c8 = 0; c8 < 8; c8++) {
      if (tid == 0) {                    // poisoned flag is negative: waits
        while (__hip_atomic_load(&flags[bt * 8 + c8], __ATOMIC_RELAXED,
                                 __HIP_MEMORY_SCOPE_AGENT) < c8 + 1)
          __builtin_amdgcn_s_sleep(2);
      }
      __syncthreads();
      __builtin_amdgcn_fence(__ATOMIC_ACQUIRE, "agent");   // reader-side inv
      // phase A: LN1+proj for this chunk (2 rows x 32 t over 4 groups)
      for (int tt = 0; tt < 16; tt++) {
        int toff = tt * 2 + (q >> 1);
        uint4 cur = *(const uint4*)(hb + (size_t)(c8 * 32 + toff) * DIM + l15 * 8);
        float hv[8];
        hv[0] = __uint_as_float(cur.x << 16); hv[1] = __uint_as_float(cur.x & 0xffff0000u);
        hv[2] = __uint_as_float(cur.y << 16); hv[3] = __uint_as_float(cur.y & 0xffff0000u);
        hv[4] = __uint_as_float(cur.z << 16); hv[5] = __uint_as_float(cur.z & 0xffff0000u);
        hv[6] = __uint_as_float(cur.w << 16); hv[7] = __uint_as_float(cur.w & 0xffff0000u);
        float s = 0.f, sq = 0.f, d[5] = {0, 0, 0, 0, 0};
#pragma unroll
        for (int j = 0; j < 8; j++) {
          float v = hv[j];
          s += v; sq += v * v;
#pragma unroll
          for (int jj = 0; jj < 5; jj++) d[jj] = fmaf(w2g[jj][j], v, d[jj]);
        }
        red_level7<0x124>(s, sq, d);
        red_level7<0x128>(s, sq, d);
        red_level7<0x39>(s, sq, d);
        red_level7<0x4E>(s, sq, d);
        float mean = s * (1.f / 128.f);
        float var  = sq * (1.f / 128.f) - mean * mean;
        float rstd = rsqrtf(var + EPSL);
        float p[5];
#pragma unroll
        for (int jj = 0; jj < 5; jj++)
          p[jj] = rstd * (d[jj] - mean * Gs[jj]) + Bs[jj];
        float psel = (l15 == 0) ? p[0] : (l15 == 1) ? p[1] :
                     (l15 == 2) ? p[2] : (l15 == 3) ? p[3] : p[4];
        if (l15 < 5) p_lds[wave][q & 1][toff][l15] = psel;
      }
      asm volatile("s_waitcnt lgkmcnt(0)" ::: "memory");   // wave-local
      // phase B: 32 serial RNN2/LN2/pool steps (group-local, 1 tanh/step)
      for (int s = 0; s < 32; s++) {
        float pv = p_lds[wave][q & 1][s][idx];
        float a = pv + t2_l;
#pragma unroll
        for (int jj = 0; jj < 5; jj++) a = fmaf(wrow[jj], h2rep[jj], a);
        float xn = tanh_fast(a);
        float s2 = dpp_sum16(xn * validf) * 0.2f;
        float dd = xn - s2;
        float v2 = dpp_sum16(dd * dd * validf) * 0.2f;
        float r2 = rsqrtf(v2 + EPSL);
        pool_l += dd * r2 * g2_l + be2_l;
        h2rep[0] = bcast16<0>(xn); h2rep[1] = bcast16<1>(xn);
        h2rep[2] = bcast16<2>(xn); h2rep[3] = bcast16<3>(xn);
        h2rep[4] = bcast16<4>(xn);
      }
    }
    float lg = pool_l * (1.f / 256.f);
    float mx = dpp_max16((l15 < 5) ? lg : -3.0e38f);
    float e  = (l15 < 5) ? __expf(lg - mx) : 0.f;
    float sm = dpp_sum16(e);
    if (q < 2 && l15 < 5)
      out[(size_t)(bt * 16 + row_l) * 5 + l15] = e / sm;
  }
}

// ============ rnn_tail_r11: fallback tail (R11, interleaved) ================
__global__ __launch_bounds__(256, 2)
void rnn_tail_r11(const unsigned short* __restrict__ hall,
                  const float* __restrict__ g1,  const float* __restrict__ be1,
                  const float* __restrict__ Wih2, const float* __restrict__ bih2,
                  const float* __restrict__ Whh2, const float* __restrict__ bhh2,
                  const float* __restrict__ g2,  const float* __restrict__ be2,
                  float* __restrict__ out)
{
  __shared__ float p_lds[4][4][8];
  const int tid  = threadIdx.x;
  const int wave = tid >> 6;
  const int lane = tid & 63;
  const int l15  = lane & 15;
  const int q    = lane >> 4;
  const int b    = blockIdx.x * 4 + wave;

  float w2g[5][8], Gs[5], Bs[5], wrow[5];
#pragma unroll
  for (int j = 0; j < 8; j++) {
    int c = l15 * 8 + j;
    float gc = g1[c];
#pragma unroll
    for (int jj = 0; jj < 5; jj++) w2g[jj][j] = Wih2[jj * DIM + c] * gc;
  }
#pragma unroll
  for (int jj = 0; jj < 5; jj++) { Gs[jj] = 0.f; Bs[jj] = 0.f; }
  for (int c = 0; c < DIM; c++) {
    float gc = g1[c], bc = be1[c];
#pragma unroll
    for (int jj = 0; jj < 5; jj++) {
      float w = Wih2[jj * DIM + c];
      Gs[jj] += w * gc; Bs[jj] += w * bc;
    }
  }
  const float validf = (l15 < 5) ? 1.f : 0.f;
  float t2_l = 0.f, g2_l = 0.f, be2_l = 0.f;
  if (l15 < 5) {
    t2_l = bih2[l15] + bhh2[l15];
    g2_l = g2[l15]; be2_l = be2[l15];
#pragma unroll
    for (int jj = 0; jj < 5; jj++) wrow[jj] = Whh2[l15 * 5 + jj];
  } else {
#pragma unroll
    for (int jj = 0; jj < 5; jj++) wrow[jj] = 0.f;
  }
  float h2rep[5];
#pragma unroll
  for (int jj = 0; jj < 5; jj++) h2rep[jj] = 0.f;
  float pool_l = 0.f;

  const unsigned short* hb = hall + (size_t)b * S_LEN * DIM;
  uint4 hpre = *(const uint4*)(hb + (size_t)q * DIM + l15 * 8);

  for (int t0 = 0; t0 < S_LEN; t0 += 4) {
    uint4 cur = hpre;
    if (t0 + 4 < S_LEN)
      hpre = *(const uint4*)(hb + (size_t)(t0 + 4 + q) * DIM + l15 * 8);
    float hv[8];
    hv[0] = __uint_as_float(cur.x << 16); hv[1] = __uint_as_float(cur.x & 0xffff0000u);
    hv[2] = __uint_as_float(cur.y << 16); hv[3] = __uint_as_float(cur.y & 0xffff0000u);
    hv[4] = __uint_as_float(cur.z << 16); hv[5] = __uint_as_float(cur.z & 0xffff0000u);
    hv[6] = __uint_as_float(cur.w << 16); hv[7] = __uint_as_float(cur.w & 0xffff0000u);
    float s = 0.f, sq = 0.f, d[5] = {0, 0, 0, 0, 0};
#pragma unroll
    for (int j = 0; j < 8; j++) {
      float v = hv[j];
      s += v; sq += v * v;
#pragma unroll
      for (int jj = 0; jj < 5; jj++) d[jj] = fmaf(w2g[jj][j], v, d[jj]);
    }
    red_level7<0x124>(s, sq, d);
    red_level7<0x128>(s, sq, d);
    red_level7<0x39>(s, sq, d);
    red_level7<0x4E>(s, sq, d);
    float mean = s * (1.f / 128.f);
    float var  = sq * (1.f / 128.f) - mean * mean;
    float rstd = rsqrtf(var + EPSL);
    float p[5];
#pragma unroll
    for (int jj = 0; jj < 5; jj++)
      p[jj] = rstd * (d[jj] - mean * Gs[jj]) + Bs[jj];
    float psel = (l15 == 0) ? p[0] : (l15 == 1) ? p[1] :
                 (l15 == 2) ? p[2] : (l15 == 3) ? p[3] : p[4];
    if (l15 < 5) p_lds[wave][q][l15] = psel;
    asm volatile("s_waitcnt lgkmcnt(0)" ::: "memory");
    const int idx = (l15 < 5) ? l15 : 0;
#pragma unroll
    for (int g = 0; g < 4; g++) {
      float pv = p_lds[wave][g][idx];
      float a = pv + t2_l;
#pragma unroll
      for (int jj = 0; jj < 5; jj++) a = fmaf(wrow[jj], h2rep[jj], a);
      float xn = tanh_fast(a);
      float s2 = dpp_sum16(xn * validf) * 0.2f;
      float dd = xn - s2;
      float v2 = dpp_sum16(dd * dd * validf) * 0.2f;
      float r2 = rsqrtf(v2 + EPSL);
      pool_l += dd * r2 * g2_l + be2_l;
      h2rep[0] = bcast16<0>(xn); h2rep[1] = bcast16<1>(xn);
      h2rep[2] = bcast16<2>(xn); h2rep[3] = bcast16<3>(xn);
      h2rep[4] = bcast16<4>(xn);
    }
  }

  float lg = pool_l * (1.f / 256.f);
  float mx = dpp_max16((l15 < 5) ? lg : -3.0e38f);
  float e  = (l15 < 5) ? __expf(lg - mx) : 0.f;
  float sm = dpp_sum16(e);
  if (q == 0 && l15 < 5) out[(size_t)b * 5 + l15] = e / sm;
}

extern "C" void kernel_launch(void* const* d_in, const int* in_sizes, int n_in,
                              void* d_out, int out_size, void* d_ws, size_t ws_size,
                              hipStream_t stream) {
  (void)in_sizes; (void)n_in; (void)out_size;
  const int*   x    = (const int*)  d_in[0];
  const float* emb  = (const float*)d_in[1];
  const float* Wih1 = (const float*)d_in[2];
  const float* bih1 = (const float*)d_in[3];
  const float* Whh1 = (const float*)d_in[4];
  const float* bhh1 = (const float*)d_in[5];
  const float* g1   = (const float*)d_in[6];
  const float* be1  = (const float*)d_in[7];
  const float* Wih2 = (const float*)d_in[8];
  const float* bih2 = (const float*)d_in[9];
  const float* Whh2 = (const float*)d_in[10];
  const float* bhh2 = (const float*)d_in[11];
  const float* g2   = (const float*)d_in[12];
  const float* be2  = (const float*)d_in[13];
  float* out = (float*)d_out;

  const size_t HBYTES = (size_t)1024 * S_LEN * DIM * 2;   // 64 MiB bf16 h
  unsigned short* hws = (unsigned short*)d_ws;

  if (ws_size >= HBYTES + 4096) {
    int* flags = (int*)((char*)d_ws + HBYTES);
    rnn_main<<<dim3(128), dim3(512), 0, stream>>>(
        x, emb, Wih1, bih1, Whh1, bhh1, g1, be1,
        Wih2, bih2, Whh2, bhh2, g2, be2, hws, flags, out);
  } else {
    // fallback: core-only mode (flags = nullptr) + R11 two-kernel tail
    rnn_main<<<dim3(64), dim3(512), 0, stream>>>(
        x, emb, Wih1, bih1, Whh1, bhh1, g1, be1,
        Wih2, bih2, Whh2, bhh2, g2, be2, hws, nullptr, out);
    rnn_tail_r11<<<dim3(256), dim3(256), 0, stream>>>(
        hws, g1, be1, Wih2, bih2, Whh2, bhh2, g2, be2, out);
  }
}